// Round 3
// baseline (1342.921 us; speedup 1.0000x reference)
//
#include <hip/hip_runtime.h>
#include <hip/hip_bf16.h>

// GGNN encoder: N=10000 nodes, H=512, T=4 edge types, E=40000 edges/type,
// L=2 layers x 2 timesteps. Inputs are FLOAT32 (per reference dtype) + int32
// edges; output float32. bf16 is used internally for MFMA (tolerance 2.7e-2).
//
// Rewrite: segment_sum(msgs), msgs = (h[src] @ Wt^T + bt) per type
//   == (segment_sum_per_type(h[src])) @ Wt^T + count[n,t]*bt    (linearity)
// -> scatter h once per step into S (N, T*H), ONE msg GEMM K=2048.
// GRU: per-gate 512-wide GEMMs with fused epilogues.
// h double-buffered across timesteps (gemm512<2> reads h as A while writing h').

#define NN 10000
#define HD 512
#define NT 4
#define NE 40000
#define CAP 32          // max edges per (target,type) bin; Poisson(mean 4)

typedef __bf16 bf16x8 __attribute__((ext_vector_type(8)));
typedef float f32x4 __attribute__((ext_vector_type(4)));
union V16 { int4 i; bf16x8 b; };

// ---------------- fp32 -> bf16 weight conversion (n divisible by 1024) ------
__global__ void f2b(const float* __restrict__ src, __hip_bfloat16* __restrict__ dst) {
    int i = (blockIdx.x * 256 + threadIdx.x) * 4;
    float4 v = *(const float4*)(src + i);
    __hip_bfloat16 o[4] = {__float2bfloat16(v.x), __float2bfloat16(v.y),
                           __float2bfloat16(v.z), __float2bfloat16(v.w)};
    *(ulong1*)(dst + i) = *(ulong1*)o;
}

// ---------------- init: h32/hb <- x ----------------
__global__ void init_h(const float* __restrict__ x,
                       float* __restrict__ h32, __hip_bfloat16* __restrict__ hb) {
    int i = blockIdx.x * 256 + threadIdx.x;
    if (i < NN * HD) { float v = x[i]; h32[i] = v; hb[i] = __float2bfloat16(v); }
}

// ---------------- bin build (once per call) ----------------
__global__ void build_bins(const int* __restrict__ edges,
                           int* __restrict__ bin_cnt, int* __restrict__ bins) {
    int i = blockIdx.x * 256 + threadIdx.x;   // over T*E
    if (i >= NT * NE) return;
    int src = edges[2 * i], tgt = edges[2 * i + 1];
    int t = i / NE;
    int b = tgt * NT + t;
    int pos = atomicAdd(&bin_cnt[b], 1);
    if (pos < CAP) bins[(size_t)b * CAP + pos] = src;
}

// ---------------- per-step scatter-sum: S[n][t*H + c] = sum h[src][c] -------
__global__ void gather_sum(const int* __restrict__ bins, const int* __restrict__ bin_cnt,
                           const __hip_bfloat16* __restrict__ h, __hip_bfloat16* __restrict__ S) {
    int b = blockIdx.x;                 // bin = n*NT + t; S row offset = b*512
    int tid = threadIdx.x;              // 256 threads, 2 cols each
    int cnt = bin_cnt[b]; if (cnt > CAP) cnt = CAP;
    const int* bl = bins + (size_t)b * CAP;
    float a0 = 0.f, a1 = 0.f;
    for (int e = 0; e < cnt; ++e) {
        int s = bl[e];                  // uniform across block
        const __hip_bfloat162* hp = (const __hip_bfloat162*)(h + (size_t)s * HD);
        __hip_bfloat162 v = hp[tid];
        a0 += __bfloat162float(v.x); a1 += __bfloat162float(v.y);
    }
    __hip_bfloat162 o;
    o.x = __float2bfloat16(a0); o.y = __float2bfloat16(a1);
    ((__hip_bfloat162*)(S + (size_t)b * HD))[tid] = o;
}

// ---------------- GEMM tile core ----------------
// 128x128 tile, BK=32, 256 thr = 4 waves (2x2 of 64x64), mfma 16x16x32 bf16.
// A/B frag: row = lane&15, k = (lane>>4)*8 + j ; C/D: col = lane&15, row = quad*4 + r.

// msg GEMM: A = S (M x 2048); W row for global k: t = k>>9, Wm[(t*512+n)*512 + (k&511)]
// epilogue: inc = acc + sum_t cnt[m,t] * b_msg[t][c], bf16 out.
__global__ __launch_bounds__(256) void gemm_msg(
    const __hip_bfloat16* __restrict__ A, const __hip_bfloat16* __restrict__ Wm,
    const float* __restrict__ bm, const int* __restrict__ cnt,
    __hip_bfloat16* __restrict__ out, int M) {
    __shared__ int4 sA[128 * 4];
    __shared__ int4 sB[128 * 4];
    int tid = threadIdx.x;
    int lane = tid & 63, wave = tid >> 6;
    int wr = wave >> 1, wc = wave & 1;
    int lm = lane & 15, quad = lane >> 4;
    int m0 = blockIdx.y * 128, n0 = blockIdx.x * 128;
    const int K = NT * HD;   // 2048

    f32x4 acc[4][4] = {};
    for (int k0 = 0; k0 < K; k0 += 32) {
        int t = k0 >> 9, kin = k0 & 511;
#pragma unroll
        for (int it = 0; it < 2; ++it) {
            int idx = it * 256 + tid;
            int row = idx >> 2, kc = idx & 3;
            int gm = m0 + row; gm = gm < M ? gm : M - 1;
            sA[idx] = *(const int4*)(A + (size_t)gm * K + k0 + kc * 8);
            sB[idx] = *(const int4*)(Wm + (size_t)(t * HD + n0 + row) * HD + kin + kc * 8);
        }
        __syncthreads();
        V16 a[4], b[4];
#pragma unroll
        for (int i = 0; i < 4; ++i) {
            a[i].i = sA[(wr * 64 + i * 16 + lm) * 4 + quad];
            b[i].i = sB[(wc * 64 + i * 16 + lm) * 4 + quad];
        }
#pragma unroll
        for (int i = 0; i < 4; ++i)
#pragma unroll
            for (int j = 0; j < 4; ++j)
                acc[i][j] = __builtin_amdgcn_mfma_f32_16x16x32_bf16(a[i].b, b[j].b, acc[i][j], 0, 0, 0);
        __syncthreads();
    }
#pragma unroll
    for (int j = 0; j < 4; ++j) {
        int c = wc * 64 + j * 16 + lm;
        float b0 = bm[n0 + c],          b1 = bm[HD + n0 + c];
        float b2 = bm[2 * HD + n0 + c], b3 = bm[3 * HD + n0 + c];
#pragma unroll
        for (int i = 0; i < 4; ++i) {
            int r0 = m0 + wr * 64 + i * 16 + quad * 4;
#pragma unroll
            for (int r = 0; r < 4; ++r) {
                int m = r0 + r;
                if (m < M) {
                    const int* cm = cnt + m * NT;
                    float bias = cm[0] * b0 + cm[1] * b1 + cm[2] * b2 + cm[3] * b3;
                    out[(size_t)m * HD + n0 + c] = __float2bfloat16(acc[i][j][r] + bias);
                }
            }
        }
    }
}

// gate GEMM: A(Mx512) @ W(512x512)^T, K=512, fused epilogue by MODE:
// MODE 0: C[m,c] = acc + bias[c]                       (fp32: Npre / R,Z pass1 / FC)
// MODE 1: C[m,c] = sigmoid(C[m,c] + acc + bias[c])     (R / Z second pass)
// MODE 2: t = acc + bias[c]; n = tanh(Np + R*t); o = (1-Z)*n + Z*h32;
//         h32 = o; hbO = bf16(o)                       (GRU combine; hbO != A)
template<int MODE>
__global__ __launch_bounds__(256) void gemm512(
    const __hip_bfloat16* __restrict__ A, const __hip_bfloat16* __restrict__ W,
    const float* __restrict__ bias, float* __restrict__ C,
    const float* __restrict__ Rg, const float* __restrict__ Zg,
    const float* __restrict__ Np, float* __restrict__ h32,
    __hip_bfloat16* __restrict__ hbO, int M) {
    __shared__ int4 sA[128 * 4];
    __shared__ int4 sB[128 * 4];
    int tid = threadIdx.x;
    int lane = tid & 63, wave = tid >> 6;
    int wr = wave >> 1, wc = wave & 1;
    int lm = lane & 15, quad = lane >> 4;
    int m0 = blockIdx.y * 128, n0 = blockIdx.x * 128;
    const int K = HD;

    f32x4 acc[4][4] = {};
    for (int k0 = 0; k0 < K; k0 += 32) {
#pragma unroll
        for (int it = 0; it < 2; ++it) {
            int idx = it * 256 + tid;
            int row = idx >> 2, kc = idx & 3;
            int gm = m0 + row; gm = gm < M ? gm : M - 1;
            sA[idx] = *(const int4*)(A + (size_t)gm * K + k0 + kc * 8);
            sB[idx] = *(const int4*)(W + (size_t)(n0 + row) * K + k0 + kc * 8);
        }
        __syncthreads();
        V16 a[4], b[4];
#pragma unroll
        for (int i = 0; i < 4; ++i) {
            a[i].i = sA[(wr * 64 + i * 16 + lm) * 4 + quad];
            b[i].i = sB[(wc * 64 + i * 16 + lm) * 4 + quad];
        }
#pragma unroll
        for (int i = 0; i < 4; ++i)
#pragma unroll
            for (int j = 0; j < 4; ++j)
                acc[i][j] = __builtin_amdgcn_mfma_f32_16x16x32_bf16(a[i].b, b[j].b, acc[i][j], 0, 0, 0);
        __syncthreads();
    }
#pragma unroll
    for (int j = 0; j < 4; ++j) {
        int c = wc * 64 + j * 16 + lm;
        float bv = bias[n0 + c];
#pragma unroll
        for (int i = 0; i < 4; ++i) {
            int r0 = m0 + wr * 64 + i * 16 + quad * 4;
#pragma unroll
            for (int r = 0; r < 4; ++r) {
                int m = r0 + r;
                if (m >= M) continue;
                size_t o = (size_t)m * HD + n0 + c;
                float v = acc[i][j][r] + bv;
                if (MODE == 0) {
                    C[o] = v;
                } else if (MODE == 1) {
                    C[o] = 1.f / (1.f + __expf(-(C[o] + v)));
                } else {
                    float nx = Np[o] + Rg[o] * v;
                    float n = 1.f - 2.f / (__expf(2.f * nx) + 1.f);   // tanh
                    float z = Zg[o];
                    float hnew = (1.f - z) * n + z * h32[o];
                    h32[o] = hnew;
                    hbO[o] = __float2bfloat16(hnew);
                }
            }
        }
    }
}

// ---------------- column max (monotone-uint trick, memset-0 init) -----------
__device__ __forceinline__ unsigned fenc(float f) {
    unsigned b = __float_as_uint(f);
    return b ^ (((int)b >> 31) | 0x80000000u);
}
__device__ __forceinline__ float fdec(unsigned u) {
    unsigned b = (u & 0x80000000u) ? (u ^ 0x80000000u) : ~u;
    return __uint_as_float(b);
}
__global__ void colmax(const float* __restrict__ out, unsigned* __restrict__ om) {
    int col = threadIdx.x;              // 512
    int r0 = blockIdx.x * 125, r1 = r0 + 125;   // 80 blocks * 125 = 10000
    float m = -INFINITY;
    for (int r = r0; r < r1; ++r) m = fmaxf(m, out[(size_t)r * HD + col]);
    atomicMax(&om[col], fenc(m));
}
__global__ void writeout(const unsigned* __restrict__ om, float* __restrict__ o) {
    int c = threadIdx.x;
    o[c] = fdec(om[c]);
}

// ---------------- launch ----------------
extern "C" void kernel_launch(void* const* d_in, const int* in_sizes, int n_in,
                              void* d_out, int out_size, void* d_ws, size_t ws_size,
                              hipStream_t stream) {
    (void)in_sizes; (void)n_in; (void)out_size; (void)ws_size;
    const float* x    = (const float*)d_in[0];
    const int*   edges= (const int*)d_in[1];
    const float* Wmsg = (const float*)d_in[2];
    const float* bmsg = (const float*)d_in[3];
    const float* Wih  = (const float*)d_in[4];
    const float* Whh  = (const float*)d_in[5];
    const float* bih  = (const float*)d_in[6];
    const float* bhh  = (const float*)d_in[7];
    const float* fcW  = (const float*)d_in[8];
    const float* fcb  = (const float*)d_in[9];
    float* out = (float*)d_out;

    char* ws = (char*)d_ws;
    size_t off = 0;
    auto alloc = [&](size_t bytes) -> void* {
        void* p = ws + off; off += (bytes + 255) & ~(size_t)255; return p;
    };
    float*          h32  = (float*)alloc((size_t)NN * HD * 4);            // 20.5 MB
    __hip_bfloat16* hbA  = (__hip_bfloat16*)alloc((size_t)NN * HD * 2);   // 10.2 MB
    __hip_bfloat16* hbB  = (__hip_bfloat16*)alloc((size_t)NN * HD * 2);   // 10.2 MB
    __hip_bfloat16* inc  = (__hip_bfloat16*)alloc((size_t)NN * HD * 2);   // 10.2 MB
    int*            bcnt = (int*)alloc((size_t)NN * NT * 4);              // 160 KB
    int*            bins = (int*)alloc((size_t)NN * NT * CAP * 4);        // 5.1 MB
    unsigned*       om   = (unsigned*)alloc(HD * 4);
    // bf16 weight mirrors
    const int NWM = 2 * NT * HD * HD;        // 2,097,152
    const int NWG = 2 * 3 * HD * HD;         // 1,572,864
    const int NFC = HD * HD;                 // 262,144
    __hip_bfloat16* WmB = (__hip_bfloat16*)alloc((size_t)NWM * 2);        // 4.2 MB
    __hip_bfloat16* WiB = (__hip_bfloat16*)alloc((size_t)NWG * 2);        // 3.1 MB
    __hip_bfloat16* WhB = (__hip_bfloat16*)alloc((size_t)NWG * 2);        // 3.1 MB
    __hip_bfloat16* WfB = (__hip_bfloat16*)alloc((size_t)NFC * 2);        // 0.5 MB
    // union region: S (41 MB) xor {R,Z,Npre} (61.4 MB) xor FC-out (20.5 MB)
    char* uni = (char*)alloc((size_t)NN * 3 * HD * 4);                    // 61.4 MB
    __hip_bfloat16* S    = (__hip_bfloat16*)uni;
    float*          Rg   = (float*)uni;
    float*          Zg   = (float*)(uni + (size_t)NN * HD * 4);
    float*          Np   = (float*)(uni + (size_t)NN * HD * 8);
    float*          outbuf = (float*)uni;
    // total ~129 MB

    hipMemsetAsync(bcnt, 0, (size_t)NN * NT * 4, stream);
    hipMemsetAsync(om, 0, HD * 4, stream);
    f2b<<<NWM / 1024, 256, 0, stream>>>(Wmsg, WmB);
    f2b<<<NWG / 1024, 256, 0, stream>>>(Wih, WiB);
    f2b<<<NWG / 1024, 256, 0, stream>>>(Whh, WhB);
    f2b<<<NFC / 1024, 256, 0, stream>>>(fcW, WfB);
    init_h<<<(NN * HD + 255) / 256, 256, 0, stream>>>(x, h32, hbA);
    build_bins<<<(NT * NE + 255) / 256, 256, 0, stream>>>(edges, bcnt, bins);

    const int MT = (NN + 127) / 128;   // 79
    const dim3 g4(4, MT);
    __hip_bfloat16* hcur = hbA;
    __hip_bfloat16* hnext = hbB;
    for (int layer = 0; layer < 2; ++layer) {
        const __hip_bfloat16* Wm = WmB + (size_t)layer * NT * HD * HD;
        const __hip_bfloat16* Wi = WiB + (size_t)layer * 3 * HD * HD;
        const __hip_bfloat16* Wh = WhB + (size_t)layer * 3 * HD * HD;
        const float* bm = bmsg + (size_t)layer * NT * HD;
        const float* bi = bih + (size_t)layer * 3 * HD;
        const float* bh = bhh + (size_t)layer * 3 * HD;
        for (int ts = 0; ts < 2; ++ts) {
            gather_sum<<<NN * NT, 256, 0, stream>>>(bins, bcnt, hcur, S);
            gemm_msg<<<g4, 256, 0, stream>>>(S, Wm, bm, bcnt, inc, NN);
            // R = sigmoid(inc@Wr^T + bi_r + h@Wr_hh^T + bh_r)
            gemm512<0><<<g4, 256, 0, stream>>>(inc, Wi, bi, Rg, nullptr, nullptr, nullptr, nullptr, nullptr, NN);
            gemm512<1><<<g4, 256, 0, stream>>>(hcur, Wh, bh, Rg, nullptr, nullptr, nullptr, nullptr, nullptr, NN);
            // Z
            gemm512<0><<<g4, 256, 0, stream>>>(inc, Wi + (size_t)HD * HD, bi + HD, Zg, nullptr, nullptr, nullptr, nullptr, nullptr, NN);
            gemm512<1><<<g4, 256, 0, stream>>>(hcur, Wh + (size_t)HD * HD, bh + HD, Zg, nullptr, nullptr, nullptr, nullptr, nullptr, NN);
            // Npre = inc@Wn^T + bi_n
            gemm512<0><<<g4, 256, 0, stream>>>(inc, Wi + (size_t)2 * HD * HD, bi + 2 * HD, Np, nullptr, nullptr, nullptr, nullptr, nullptr, NN);
            // GRU combine: n = tanh(Np + R*(h@Wn_hh^T + bh_n)); h' = (1-Z)n + Z h
            gemm512<2><<<g4, 256, 0, stream>>>(hcur, Wh + (size_t)2 * HD * HD, bh + 2 * HD, nullptr, Rg, Zg, Np, h32, hnext, NN);
            __hip_bfloat16* tmp = hcur; hcur = hnext; hnext = tmp;
        }
    }
    gemm512<0><<<g4, 256, 0, stream>>>(hcur, WfB, fcb, outbuf, nullptr, nullptr, nullptr, nullptr, nullptr, NN);
    colmax<<<80, 512, 0, stream>>>(outbuf, om);
    writeout<<<1, 512, 0, stream>>>(om, out);
}

// Round 4
// 858.318 us; speedup vs baseline: 1.5646x; 1.5646x over previous
//
#include <hip/hip_runtime.h>
#include <hip/hip_bf16.h>

// GGNN encoder: N=10000, H=512, T=4, E=40000, L=2 x 2 timesteps.
// fp32 inputs, fp32 output, bf16 MFMA internally.
//
// Per step:
//   Msg  = h @ Wmsg_cat^T          (N x 2048, K=512)   [MODE 0, grid 16x79]
//   inc  = gather-sum(Msg) + cnt*b (N x 512)           [gather_msum]
//   RZ   = sigmoid([inc|h] @ Wrz^T + b)  (N x 1024, K=1024) [MODE 1, grid 8x79]
//   NB   = inc @ Win^T + bi_n      (N x 512)           [MODE 2]
//   h'   = GRU-combine fused into h @ Whn^T epilogue   [MODE 3]
// Final: FC + column-max fused     [MODE 4] -> writeout.
// AB = [inc | h] (N x 1024), double-buffered across steps.

#define NN 10000
#define HD 512
#define NT 4
#define NE 40000
#define CAP 32

typedef __bf16 bf16x8 __attribute__((ext_vector_type(8)));
typedef float f32x4 __attribute__((ext_vector_type(4)));
union V16 { int4 i; bf16x8 b; };

typedef __attribute__((address_space(1))) const unsigned int gu32;
typedef __attribute__((address_space(3))) unsigned int lu32;
__device__ __forceinline__ void gll16(const void* g, void* l) {
    __builtin_amdgcn_global_load_lds((gu32*)g, (lu32*)l, 16, 0, 0);
}

__device__ __forceinline__ float bf2f(__hip_bfloat16 v) { return __bfloat162float(v); }

// ---------------- weight prep ----------------
__global__ void f2b(const float* __restrict__ src, __hip_bfloat16* __restrict__ dst) {
    int i = (blockIdx.x * 256 + threadIdx.x) * 4;
    float4 v = *(const float4*)(src + i);
    __hip_bfloat16 o[4] = {__float2bfloat16(v.x), __float2bfloat16(v.y),
                           __float2bfloat16(v.z), __float2bfloat16(v.w)};
    *(ulong1*)(dst + i) = *(ulong1*)o;
}
// Wrz[l][j][0:512]=Wih[l][j], [512:1024]=Whh[l][j]  (j<1024), flat 2*1024*1024
__global__ void prep_wrz(const float* __restrict__ Wih, const float* __restrict__ Whh,
                         __hip_bfloat16* __restrict__ dst) {
    int i = (blockIdx.x * 256 + threadIdx.x) * 4;
    int l = i >> 20, r = (i >> 10) & 1023, c = i & 1023;
    const float* s = (c < 512) ? (Wih + (size_t)l * 786432 + (size_t)r * 512 + c)
                               : (Whh + (size_t)l * 786432 + (size_t)r * 512 + (c - 512));
    float4 v = *(const float4*)s;
    __hip_bfloat16 o[4] = {__float2bfloat16(v.x), __float2bfloat16(v.y),
                           __float2bfloat16(v.z), __float2bfloat16(v.w)};
    *(ulong1*)(dst + i) = *(ulong1*)o;
}
// n-gate rows 1024..1535 of each layer's (1536x512) weight, flat 2*512*512
__global__ void prep_wn(const float* __restrict__ W, __hip_bfloat16* __restrict__ dst) {
    int i = (blockIdx.x * 256 + threadIdx.x) * 4;
    int l = i >> 18, rem = i & 262143;
    const float* s = W + (size_t)l * 786432 + 524288 + rem;
    float4 v = *(const float4*)s;
    __hip_bfloat16 o[4] = {__float2bfloat16(v.x), __float2bfloat16(v.y),
                           __float2bfloat16(v.z), __float2bfloat16(v.w)};
    *(ulong1*)(dst + i) = *(ulong1*)o;
}

// ---------------- init: h32 <- x, AB0 h-slot <- bf16(x) ----------------
__global__ void init_h(const float* __restrict__ x, float* __restrict__ h32,
                       __hip_bfloat16* __restrict__ ab) {
    int i = (blockIdx.x * 256 + threadIdx.x) * 4;       // NN*HD divisible by 4
    if (i >= NN * HD) return;
    float4 v = *(const float4*)(x + i);
    *(float4*)(h32 + i) = v;
    int m = i >> 9, c = i & 511;
    __hip_bfloat16 o[4] = {__float2bfloat16(v.x), __float2bfloat16(v.y),
                           __float2bfloat16(v.z), __float2bfloat16(v.w)};
    *(ulong1*)(ab + (size_t)m * 1024 + 512 + c) = *(ulong1*)o;
}

// ---------------- bins ----------------
__global__ void build_bins(const int* __restrict__ edges,
                           int* __restrict__ bin_cnt, int* __restrict__ bins) {
    int i = blockIdx.x * 256 + threadIdx.x;
    if (i >= NT * NE) return;
    int src = edges[2 * i], tgt = edges[2 * i + 1];
    int t = i / NE;
    int b = tgt * NT + t;
    int pos = atomicAdd(&bin_cnt[b], 1);
    if (pos < CAP) bins[(size_t)b * CAP + pos] = src;
}

// ---------------- gather: inc[n][c] = sum_t sum_src Msg[src][t*512+c] + cnt*bm ----
__global__ __launch_bounds__(256) void gather_msum(
    const int* __restrict__ bins, const int* __restrict__ bcnt,
    const float* __restrict__ bm, const __hip_bfloat16* __restrict__ Msg,
    __hip_bfloat16* __restrict__ inc) {
    int wave = threadIdx.x >> 6, lane = threadIdx.x & 63;
    int n = blockIdx.x * 4 + wave;          // grid 2500, exact
    int co = lane * 8;
    float acc[8] = {0, 0, 0, 0, 0, 0, 0, 0};
#pragma unroll
    for (int t = 0; t < NT; ++t) {
        int bi = n * NT + t;
        int cnt = bcnt[bi]; if (cnt > CAP) cnt = CAP;
        const int* bl = bins + (size_t)bi * CAP;
        for (int e = 0; e < cnt; ++e) {
            int src = bl[e];
            V16 v; v.i = *(const int4*)(Msg + (size_t)src * 2048 + t * 512 + co);
#pragma unroll
            for (int k = 0; k < 8; ++k) acc[k] += (float)v.b[k];
        }
        float4 b0 = *(const float4*)(bm + t * 512 + co);
        float4 b1 = *(const float4*)(bm + t * 512 + co + 4);
        float fc = (float)cnt;
        acc[0] += fc * b0.x; acc[1] += fc * b0.y; acc[2] += fc * b0.z; acc[3] += fc * b0.w;
        acc[4] += fc * b1.x; acc[5] += fc * b1.y; acc[6] += fc * b1.z; acc[7] += fc * b1.w;
    }
    V16 o;
#pragma unroll
    for (int k = 0; k < 8; ++k) o.b[k] = (__bf16)acc[k];
    *(int4*)(inc + (size_t)n * 1024 + co) = o.i;
}

// ---------------- monotone-uint float max encoding ----------------
__device__ __forceinline__ unsigned fenc(float f) {
    unsigned b = __float_as_uint(f);
    return b ^ (((int)b >> 31) | 0x80000000u);
}
__device__ __forceinline__ float fdec(unsigned u) {
    unsigned b = (u & 0x80000000u) ? (u ^ 0x80000000u) : ~u;
    return __uint_as_float(b);
}

// ---------------- GEMM: out = A(NNxK,lda) @ W(NOUTxK)^T, 128x128 tile --------
// MODE 0: obf[m*ldo+col] = bf16(acc)                       (Msg)
// MODE 1: obf = bf16(sigmoid(acc + b0[col] + b1[col]))     (RZ)
// MODE 2: obf = bf16(acc + b0[col])                        (i_n)
// MODE 3: v=acc+b0[col]; GRU combine -> h32, obf(=ABnxt h-slot)
// MODE 4: v=acc+b0[col]; column max -> om
template<int MODE>
__global__ __launch_bounds__(256) void gemm(
    const __hip_bfloat16* __restrict__ A, int lda, int K,
    const __hip_bfloat16* __restrict__ W,
    const float* __restrict__ b0, const float* __restrict__ b1,
    const __hip_bfloat16* __restrict__ RZ, const __hip_bfloat16* __restrict__ NB,
    float* __restrict__ h32, __hip_bfloat16* __restrict__ obf, int ldo,
    unsigned* __restrict__ om) {
    __shared__ int4 sA4[512];
    __shared__ int4 sB4[512];
    __shared__ unsigned sm[128];
    __hip_bfloat16* sAp = (__hip_bfloat16*)sA4;
    __hip_bfloat16* sBp = (__hip_bfloat16*)sB4;
    int tid = threadIdx.x;
    int lane = tid & 63, wave = tid >> 6;
    int wr = wave >> 1, wc = wave & 1;
    int lm = lane & 15, quad = lane >> 4;
    int m0 = blockIdx.y * 128, n0 = blockIdx.x * 128;

    f32x4 acc[4][4] = {};
    for (int k0 = 0; k0 < K; k0 += 32) {
#pragma unroll
        for (int it = 0; it < 2; ++it) {
            int idx = it * 256 + tid;
            int row = idx >> 2, kc = idx & 3;
            int gm = m0 + row; gm = gm < NN ? gm : NN - 1;
            gll16(A + (size_t)gm * lda + k0 + kc * 8, sAp + idx * 8);
            gll16(W + (size_t)(n0 + row) * K + k0 + kc * 8, sBp + idx * 8);
        }
        __syncthreads();
        V16 a[4], b[4];
#pragma unroll
        for (int i = 0; i < 4; ++i) {
            a[i].i = sA4[(wr * 64 + i * 16 + lm) * 4 + quad];
            b[i].i = sB4[(wc * 64 + i * 16 + lm) * 4 + quad];
        }
#pragma unroll
        for (int i = 0; i < 4; ++i)
#pragma unroll
            for (int j = 0; j < 4; ++j)
                acc[i][j] = __builtin_amdgcn_mfma_f32_16x16x32_bf16(a[i].b, b[j].b, acc[i][j], 0, 0, 0);
        __syncthreads();
    }
    if (MODE == 4) {
        if (tid < 128) sm[tid] = 0;
        __syncthreads();
    }
#pragma unroll
    for (int j = 0; j < 4; ++j) {
        int c = wc * 64 + j * 16 + lm;
        int col = n0 + c;
        float bias = (MODE == 0) ? 0.f : b0[col] + ((MODE == 1) ? b1[col] : 0.f);
        float mx = -INFINITY;
#pragma unroll
        for (int i = 0; i < 4; ++i) {
            int r0 = m0 + wr * 64 + i * 16 + quad * 4;
#pragma unroll
            for (int r = 0; r < 4; ++r) {
                int m = r0 + r;
                if (m >= NN) continue;
                float v = acc[i][j][r] + bias;
                if (MODE == 0 || MODE == 2) {
                    obf[(size_t)m * ldo + col] = __float2bfloat16(v);
                } else if (MODE == 1) {
                    obf[(size_t)m * ldo + col] = __float2bfloat16(1.f / (1.f + __expf(-v)));
                } else if (MODE == 3) {
                    float rg = bf2f(RZ[(size_t)m * 1024 + col]);
                    float zg = bf2f(RZ[(size_t)m * 1024 + 512 + col]);
                    float inn = bf2f(NB[(size_t)m * 512 + col]);
                    float nx = inn + rg * v;
                    float n = 1.f - 2.f / (__expf(2.f * nx) + 1.f);
                    size_t o = (size_t)m * 512 + col;
                    float hnew = (1.f - zg) * n + zg * h32[o];
                    h32[o] = hnew;
                    obf[(size_t)m * ldo + col] = __float2bfloat16(hnew);
                } else {
                    mx = fmaxf(mx, v);
                }
            }
        }
        if (MODE == 4) atomicMax(&sm[c], fenc(mx));
    }
    if (MODE == 4) {
        __syncthreads();
        if (tid < 128) atomicMax(&om[n0 + tid], sm[tid]);
    }
}

__global__ void writeout(const unsigned* __restrict__ om, float* __restrict__ o) {
    int c = threadIdx.x;
    o[c] = fdec(om[c]);
}

// ---------------- launch ----------------
extern "C" void kernel_launch(void* const* d_in, const int* in_sizes, int n_in,
                              void* d_out, int out_size, void* d_ws, size_t ws_size,
                              hipStream_t stream) {
    (void)in_sizes; (void)n_in; (void)out_size; (void)ws_size;
    const float* x    = (const float*)d_in[0];
    const int*   edges= (const int*)d_in[1];
    const float* Wmsg = (const float*)d_in[2];
    const float* bmsg = (const float*)d_in[3];
    const float* Wih  = (const float*)d_in[4];
    const float* Whh  = (const float*)d_in[5];
    const float* bih  = (const float*)d_in[6];
    const float* bhh  = (const float*)d_in[7];
    const float* fcW  = (const float*)d_in[8];
    const float* fcb  = (const float*)d_in[9];
    float* out = (float*)d_out;

    char* ws = (char*)d_ws;
    size_t off = 0;
    auto alloc = [&](size_t bytes) -> void* {
        void* p = ws + off; off += (bytes + 255) & ~(size_t)255; return p;
    };
    float*          h32  = (float*)alloc((size_t)NN * HD * 4);              // 20.5 MB
    __hip_bfloat16* abA  = (__hip_bfloat16*)alloc((size_t)NN * 1024 * 2);   // 20.5 MB
    __hip_bfloat16* abB  = (__hip_bfloat16*)alloc((size_t)NN * 1024 * 2);   // 20.5 MB
    int*            bcnt = (int*)alloc((size_t)NN * NT * 4);                // 160 KB
    int*            bins = (int*)alloc((size_t)NN * NT * CAP * 4);          // 5.1 MB
    unsigned*       om   = (unsigned*)alloc(HD * 4);
    __hip_bfloat16* WmB  = (__hip_bfloat16*)alloc((size_t)2 * 2048 * 512 * 2);  // 4.2 MB
    __hip_bfloat16* Wrz  = (__hip_bfloat16*)alloc((size_t)2 * 1024 * 1024 * 2); // 4.2 MB
    __hip_bfloat16* Wni  = (__hip_bfloat16*)alloc((size_t)2 * 512 * 512 * 2);   // 1.05 MB
    __hip_bfloat16* Wnh  = (__hip_bfloat16*)alloc((size_t)2 * 512 * 512 * 2);   // 1.05 MB
    __hip_bfloat16* WfB  = (__hip_bfloat16*)alloc((size_t)512 * 512 * 2);       // 0.5 MB
    // union: Msg (41 MB) xor { RZ (20.5) + NB (10.2) }
    char* uni = (char*)alloc((size_t)NN * 2048 * 2);                        // 41 MB
    __hip_bfloat16* Msg = (__hip_bfloat16*)uni;
    __hip_bfloat16* RZ  = (__hip_bfloat16*)uni;
    __hip_bfloat16* NB  = (__hip_bfloat16*)(uni + (size_t)NN * 1024 * 2);
    // total ~119 MB

    hipMemsetAsync(bcnt, 0, (size_t)NN * NT * 4, stream);
    hipMemsetAsync(om, 0, HD * 4, stream);
    f2b<<<2 * 2048 * 512 / 1024, 256, 0, stream>>>(Wmsg, WmB);
    prep_wrz<<<2 * 1024 * 1024 / 1024, 256, 0, stream>>>(Wih, Whh, Wrz);
    prep_wn<<<2 * 512 * 512 / 1024, 256, 0, stream>>>(Wih, Wni);
    prep_wn<<<2 * 512 * 512 / 1024, 256, 0, stream>>>(Whh, Wnh);
    f2b<<<512 * 512 / 1024, 256, 0, stream>>>(fcW, WfB);
    init_h<<<NN * HD / 1024, 256, 0, stream>>>(x, h32, abA);
    build_bins<<<(NT * NE + 255) / 256, 256, 0, stream>>>(edges, bcnt, bins);

    const int MT = (NN + 127) / 128;   // 79
    for (int s = 0; s < 4; ++s) {
        int layer = s >> 1;
        __hip_bfloat16* cur = (s & 1) ? abB : abA;
        __hip_bfloat16* nxt = (s & 1) ? abA : abB;
        const __hip_bfloat16* Wm = WmB + (size_t)layer * 2048 * 512;
        const __hip_bfloat16* Wz = Wrz + (size_t)layer * 1024 * 1024;
        const __hip_bfloat16* Wn_i = Wni + (size_t)layer * 512 * 512;
        const __hip_bfloat16* Wn_h = Wnh + (size_t)layer * 512 * 512;
        const float* bm = bmsg + (size_t)layer * 2048;
        const float* bi = bih + (size_t)layer * 1536;
        const float* bh = bhh + (size_t)layer * 1536;

        // Msg = h @ Wm^T  (N-out 2048, K=512)
        gemm<0><<<dim3(16, MT), 256, 0, stream>>>(cur + 512, 1024, 512, Wm,
            nullptr, nullptr, nullptr, nullptr, nullptr, Msg, 2048, nullptr);
        // inc = gather(Msg) + cnt*bm  -> cur[0:512]
        gather_msum<<<NN / 4, 256, 0, stream>>>(bins, bcnt, bm, Msg, cur);
        // RZ = sigmoid([inc|h] @ Wrz^T + bi+bh)  (N-out 1024, K=1024)
        gemm<1><<<dim3(8, MT), 256, 0, stream>>>(cur, 1024, 1024, Wz,
            bi, bh, nullptr, nullptr, nullptr, RZ, 1024, nullptr);
        // NB = inc @ Wni^T + bi_n
        gemm<2><<<dim3(4, MT), 256, 0, stream>>>(cur, 1024, 512, Wn_i,
            bi + 1024, nullptr, nullptr, nullptr, nullptr, NB, 512, nullptr);
        // GRU combine fused into h @ Wnh^T epilogue -> h32, nxt h-slot
        gemm<3><<<dim3(4, MT), 256, 0, stream>>>(cur + 512, 1024, 512, Wn_h,
            bh + 1024, nullptr, RZ, NB, h32, nxt + 512, 1024, nullptr);
    }
    // FC + column max (final h is in abA h-slot after 4 steps)
    gemm<4><<<dim3(4, MT), 256, 0, stream>>>(abA + 512, 1024, 512, WfB,
        fcb, nullptr, nullptr, nullptr, nullptr, nullptr, 0, om);
    writeout<<<1, 512, 0, stream>>>(om, out);
}

// Round 5
// 835.710 us; speedup vs baseline: 1.6069x; 1.0271x over previous
//
#include <hip/hip_runtime.h>
#include <hip/hip_bf16.h>

// GGNN encoder: N=10000, H=512, T=4, E=40000, L=2 x 2 timesteps.
// fp32 inputs, fp32 output, bf16 MFMA internally.
//
// Per step:
//   Msg  = h @ Wmsg_cat^T                (N x 2048, K=512)  [MODE 0, GX=16]
//   inc  = gather-sum(Msg) + cnt*b       (N x 512)          [gather_msum]
//   RZN  = [sig|sig|id]([inc|h] @ Wrzn^T + b) (N x 1536, K=1024) [MODE 1, GX=12]
//          (n-gate rows of Wrzn zero-padded on h-half -> i_n exactly)
//   h'   = GRU combine fused into h @ Wnh^T epilogue        [MODE 2, GX=4]
// Final: FC + column-max fused [MODE 3] -> writeout.
// AB = [inc | h] (N x 1024) double-buffered. All GEMMs use global_load_lds
// staging and an XCD swizzle (blocks sharing an A row-stripe -> same XCD L2).

#define NN 10000
#define HD 512
#define NT 4
#define NE 40000
#define CAP 32
#define GYROWS 79          // ceil(10000/128)

typedef __bf16 bf16x8 __attribute__((ext_vector_type(8)));
typedef float f32x4 __attribute__((ext_vector_type(4)));
union V16 { int4 i; bf16x8 b; };

typedef __attribute__((address_space(1))) const unsigned int gu32;
typedef __attribute__((address_space(3))) unsigned int lu32;
__device__ __forceinline__ void gll16(const void* g, void* l) {
    __builtin_amdgcn_global_load_lds((gu32*)g, (lu32*)l, 16, 0, 0);
}

__device__ __forceinline__ float bf2f(__hip_bfloat16 v) { return __bfloat162float(v); }

__device__ __forceinline__ void f2b4(const float* __restrict__ s,
                                     __hip_bfloat16* __restrict__ d, int i) {
    float4 v = *(const float4*)(s + i);
    __hip_bfloat16 o[4] = {__float2bfloat16(v.x), __float2bfloat16(v.y),
                           __float2bfloat16(v.z), __float2bfloat16(v.w)};
    *(ulong1*)(d + i) = *(ulong1*)o;
}

// ---------------- fused prep: weights->bf16, Wrzn build, init, bins ---------
// SEG0 WmB 2048 blk | SEG1 Wrzn 3072 | SEG2 Wnh 512 | SEG3 WfB 256 |
// SEG4 init_h 5000 | SEG5 build_bins 625.  (1024 elems/blk for convs)
__global__ void prep_all(const float* __restrict__ Wmsg, const float* __restrict__ Wih,
                         const float* __restrict__ Whh, const float* __restrict__ fcW,
                         const float* __restrict__ x, const int* __restrict__ edges,
                         __hip_bfloat16* __restrict__ WmB, __hip_bfloat16* __restrict__ Wrzn,
                         __hip_bfloat16* __restrict__ WnhB, __hip_bfloat16* __restrict__ WfB,
                         float* __restrict__ h32, __hip_bfloat16* __restrict__ ab,
                         int* __restrict__ bcnt, int* __restrict__ bins) {
    int blk = blockIdx.x, tid = threadIdx.x;
    if (blk < 2048) { f2b4(Wmsg, WmB, blk * 1024 + tid * 4); return; }
    blk -= 2048;
    if (blk < 3072) {            // Wrzn: per layer 1536 rows x 1024 cols
        int i = blk * 1024 + tid * 4;
        int l = (i >= 1572864);
        int rem = i - l * 1572864;
        int r = rem >> 10, c = i & 1023;
        __hip_bfloat16 o[4];
        if (c < 512) {
            float4 v = *(const float4*)(Wih + (size_t)l * 786432 + (size_t)r * 512 + c);
            o[0] = __float2bfloat16(v.x); o[1] = __float2bfloat16(v.y);
            o[2] = __float2bfloat16(v.z); o[3] = __float2bfloat16(v.w);
        } else if (r < 1024) {
            float4 v = *(const float4*)(Whh + (size_t)l * 786432 + (size_t)r * 512 + (c - 512));
            o[0] = __float2bfloat16(v.x); o[1] = __float2bfloat16(v.y);
            o[2] = __float2bfloat16(v.z); o[3] = __float2bfloat16(v.w);
        } else {                 // n-gate rows, h-half: zero
            o[0] = o[1] = o[2] = o[3] = __float2bfloat16(0.f);
        }
        *(ulong1*)(Wrzn + i) = *(ulong1*)o;
        return;
    }
    blk -= 3072;
    if (blk < 512) {             // Wnh: rows 1024..1535 of each layer's Whh
        int i = blk * 1024 + tid * 4;
        int l = i >> 18, rem = i & 262143;
        f2b4(Whh + (size_t)l * 786432 + 524288 - ((size_t)l * 786432 + 524288) + 0, WnhB, 0);
        // (avoid fancy pointer math pitfalls; do it directly:)
        float4 v = *(const float4*)(Whh + (size_t)l * 786432 + 524288 + rem);
        __hip_bfloat16 o[4] = {__float2bfloat16(v.x), __float2bfloat16(v.y),
                               __float2bfloat16(v.z), __float2bfloat16(v.w)};
        *(ulong1*)(WnhB + i) = *(ulong1*)o;
        return;
    }
    blk -= 512;
    if (blk < 256) { f2b4(fcW, WfB, blk * 1024 + tid * 4); return; }
    blk -= 256;
    if (blk < 5000) {            // init: h32 <- x, abA h-slot <- bf16(x)
        int i = blk * 1024 + tid * 4;
        float4 v = *(const float4*)(x + i);
        *(float4*)(h32 + i) = v;
        int m = i >> 9, c = i & 511;
        __hip_bfloat16 o[4] = {__float2bfloat16(v.x), __float2bfloat16(v.y),
                               __float2bfloat16(v.z), __float2bfloat16(v.w)};
        *(ulong1*)(ab + (size_t)m * 1024 + 512 + c) = *(ulong1*)o;
        return;
    }
    blk -= 5000;
    {                            // build_bins
        int i = blk * 256 + tid;
        if (i >= NT * NE) return;
        int src = edges[2 * i], tgt = edges[2 * i + 1];
        int t = i / NE;
        int b = tgt * NT + t;
        int pos = atomicAdd(&bcnt[b], 1);
        if (pos < CAP) bins[(size_t)b * CAP + pos] = src;
    }
}

// ---------------- gather: inc[n][c] = sum_t sum_src Msg[src][t*512+c] + cnt*bm
__global__ __launch_bounds__(256) void gather_msum(
    const int* __restrict__ bins, const int* __restrict__ bcnt,
    const float* __restrict__ bm, const __hip_bfloat16* __restrict__ Msg,
    __hip_bfloat16* __restrict__ inc) {
    int wave = threadIdx.x >> 6, lane = threadIdx.x & 63;
    int n = blockIdx.x * 4 + wave;
    int co = lane * 8;
    float acc[8] = {0, 0, 0, 0, 0, 0, 0, 0};
#pragma unroll
    for (int t = 0; t < NT; ++t) {
        int bi = n * NT + t;
        int cnt = bcnt[bi]; if (cnt > CAP) cnt = CAP;
        const int* bl = bins + (size_t)bi * CAP;
        for (int e = 0; e < cnt; ++e) {
            int src = bl[e];
            V16 v; v.i = *(const int4*)(Msg + (size_t)src * 2048 + t * 512 + co);
#pragma unroll
            for (int k = 0; k < 8; ++k) acc[k] += (float)v.b[k];
        }
        float4 b0 = *(const float4*)(bm + t * 512 + co);
        float4 b1 = *(const float4*)(bm + t * 512 + co + 4);
        float fc = (float)cnt;
        acc[0] += fc * b0.x; acc[1] += fc * b0.y; acc[2] += fc * b0.z; acc[3] += fc * b0.w;
        acc[4] += fc * b1.x; acc[5] += fc * b1.y; acc[6] += fc * b1.z; acc[7] += fc * b1.w;
    }
    V16 o;
#pragma unroll
    for (int k = 0; k < 8; ++k) o.b[k] = (__bf16)acc[k];
    *(int4*)(inc + (size_t)n * 1024 + co) = o.i;
}

// ---------------- monotone-uint float max encoding ----------------
__device__ __forceinline__ unsigned fenc(float f) {
    unsigned b = __float_as_uint(f);
    return b ^ (((int)b >> 31) | 0x80000000u);
}
__device__ __forceinline__ float fdec(unsigned u) {
    unsigned b = (u & 0x80000000u) ? (u ^ 0x80000000u) : ~u;
    return __uint_as_float(b);
}

// ---------------- GEMM: out = A(NNxK,lda) @ W^T, 128x128 tile, XCD swizzle ---
// MODE 0: obf[m*2048+col] = bf16(acc)                              (Msg)
// MODE 1: v=acc+b0+b1(col<1024); obf = bf16(col<1024?sigmoid(v):v) (RZN)
// MODE 2: v=acc+b0; GRU combine with RZN -> h32, obf (next h-slot)
// MODE 3: v=acc+b0; column max -> om                               (FC)
template<int MODE, int GX>
__global__ __launch_bounds__(256) void gemm(
    const __hip_bfloat16* __restrict__ A, int lda, int K,
    const __hip_bfloat16* __restrict__ W,
    const float* __restrict__ b0, const float* __restrict__ b1,
    const __hip_bfloat16* __restrict__ RZN,
    float* __restrict__ h32, __hip_bfloat16* __restrict__ obf, int ldo,
    unsigned* __restrict__ om) {
    __shared__ int4 sA4[512];
    __shared__ int4 sB4[512];
    __shared__ unsigned sm[128];
    __hip_bfloat16* sAp = (__hip_bfloat16*)sA4;
    __hip_bfloat16* sBp = (__hip_bfloat16*)sB4;
    // XCD swizzle: consecutive block ids round-robin XCDs; keep all GX
    // column-tiles of one row-stripe on ONE XCD so A stays in its L2.
    int bid = blockIdx.x;
    int xcd = bid & 7, slot = bid >> 3;
    int brow = (slot / GX) * 8 + xcd;
    if (brow >= GYROWS) return;
    int bcol = slot % GX;
    int m0 = brow * 128, n0 = bcol * 128;

    int tid = threadIdx.x;
    int lane = tid & 63, wave = tid >> 6;
    int wr = wave >> 1, wc = wave & 1;
    int lm = lane & 15, quad = lane >> 4;

    f32x4 acc[4][4] = {};
    for (int k0 = 0; k0 < K; k0 += 32) {
#pragma unroll
        for (int it = 0; it < 2; ++it) {
            int idx = it * 256 + tid;
            int row = idx >> 2, kc = idx & 3;
            int gm = m0 + row; gm = gm < NN ? gm : NN - 1;
            gll16(A + (size_t)gm * lda + k0 + kc * 8, sAp + idx * 8);
            gll16(W + (size_t)(n0 + row) * K + k0 + kc * 8, sBp + idx * 8);
        }
        __syncthreads();
        V16 a[4], b[4];
#pragma unroll
        for (int i = 0; i < 4; ++i) {
            a[i].i = sA4[(wr * 64 + i * 16 + lm) * 4 + quad];
            b[i].i = sB4[(wc * 64 + i * 16 + lm) * 4 + quad];
        }
#pragma unroll
        for (int i = 0; i < 4; ++i)
#pragma unroll
            for (int j = 0; j < 4; ++j)
                acc[i][j] = __builtin_amdgcn_mfma_f32_16x16x32_bf16(a[i].b, b[j].b, acc[i][j], 0, 0, 0);
        __syncthreads();
    }
    if (MODE == 3) {
        if (tid < 128) sm[tid] = 0;
        __syncthreads();
    }
#pragma unroll
    for (int j = 0; j < 4; ++j) {
        int c = wc * 64 + j * 16 + lm;
        int col = n0 + c;
        float bias = 0.f;
        if (MODE == 1) bias = b0[col] + (col < 1024 ? b1[col] : 0.f);
        if (MODE == 2 || MODE == 3) bias = b0[col];
        float mx = -INFINITY;
#pragma unroll
        for (int i = 0; i < 4; ++i) {
            int r0 = m0 + wr * 64 + i * 16 + quad * 4;
#pragma unroll
            for (int r = 0; r < 4; ++r) {
                int m = r0 + r;
                if (m >= NN) continue;
                float v = acc[i][j][r] + bias;
                if (MODE == 0) {
                    obf[(size_t)m * 2048 + col] = __float2bfloat16(v);
                } else if (MODE == 1) {
                    float o = (col < 1024) ? 1.f / (1.f + __expf(-v)) : v;
                    obf[(size_t)m * 1536 + col] = __float2bfloat16(o);
                } else if (MODE == 2) {
                    size_t rz = (size_t)m * 1536;
                    float rg = bf2f(RZN[rz + col]);
                    float zg = bf2f(RZN[rz + 512 + col]);
                    float inn = bf2f(RZN[rz + 1024 + col]);
                    float nx = inn + rg * v;
                    float n = 1.f - 2.f / (__expf(2.f * nx) + 1.f);
                    size_t o = (size_t)m * 512 + col;
                    float hnew = (1.f - zg) * n + zg * h32[o];
                    h32[o] = hnew;
                    obf[(size_t)m * ldo + col] = __float2bfloat16(hnew);
                } else {
                    mx = fmaxf(mx, v);
                }
            }
        }
        if (MODE == 3) atomicMax(&sm[c], fenc(mx));
    }
    if (MODE == 3) {
        __syncthreads();
        if (tid < 128) atomicMax(&om[n0 + tid], sm[tid]);
    }
}

__global__ void writeout(const unsigned* __restrict__ om, float* __restrict__ o) {
    int c = threadIdx.x;
    o[c] = fdec(om[c]);
}

// ---------------- launch ----------------
extern "C" void kernel_launch(void* const* d_in, const int* in_sizes, int n_in,
                              void* d_out, int out_size, void* d_ws, size_t ws_size,
                              hipStream_t stream) {
    (void)in_sizes; (void)n_in; (void)out_size; (void)ws_size;
    const float* x    = (const float*)d_in[0];
    const int*   edges= (const int*)d_in[1];
    const float* Wmsg = (const float*)d_in[2];
    const float* bmsg = (const float*)d_in[3];
    const float* Wih  = (const float*)d_in[4];
    const float* Whh  = (const float*)d_in[5];
    const float* bih  = (const float*)d_in[6];
    const float* bhh  = (const float*)d_in[7];
    const float* fcW  = (const float*)d_in[8];
    const float* fcb  = (const float*)d_in[9];
    float* out = (float*)d_out;

    char* ws = (char*)d_ws;
    size_t off = 0;
    auto alloc = [&](size_t bytes) -> void* {
        void* p = ws + off; off += (bytes + 255) & ~(size_t)255; return p;
    };
    float*          h32  = (float*)alloc((size_t)NN * HD * 4);              // 20.5 MB
    __hip_bfloat16* abA  = (__hip_bfloat16*)alloc((size_t)NN * 1024 * 2);   // 20.5 MB
    __hip_bfloat16* abB  = (__hip_bfloat16*)alloc((size_t)NN * 1024 * 2);   // 20.5 MB
    int*            bcnt = (int*)alloc((size_t)NN * NT * 4);                // 160 KB
    int*            bins = (int*)alloc((size_t)NN * NT * CAP * 4);          // 5.1 MB
    unsigned*       om   = (unsigned*)alloc(HD * 4);
    __hip_bfloat16* WmB  = (__hip_bfloat16*)alloc((size_t)2 * 2048 * 512 * 2);  // 4.2 MB
    __hip_bfloat16* Wrzn = (__hip_bfloat16*)alloc((size_t)2 * 1536 * 1024 * 2); // 6.3 MB
    __hip_bfloat16* Wnh  = (__hip_bfloat16*)alloc((size_t)2 * 512 * 512 * 2);   // 1.05 MB
    __hip_bfloat16* WfB  = (__hip_bfloat16*)alloc((size_t)512 * 512 * 2);       // 0.5 MB
    // union: Msg (41 MB) xor RZN (30.7 MB)
    char* uni = (char*)alloc((size_t)NN * 2048 * 2);                        // 41 MB
    __hip_bfloat16* Msg = (__hip_bfloat16*)uni;
    __hip_bfloat16* RZN = (__hip_bfloat16*)uni;
    // total ~120 MB

    hipMemsetAsync(bcnt, 0, (size_t)NN * NT * 4, stream);
    hipMemsetAsync(om, 0, HD * 4, stream);
    prep_all<<<2048 + 3072 + 512 + 256 + 5000 + 625, 256, 0, stream>>>(
        Wmsg, Wih, Whh, fcW, x, edges, WmB, Wrzn, Wnh, WfB, h32, abA, bcnt, bins);

    for (int s = 0; s < 4; ++s) {
        int layer = s >> 1;
        __hip_bfloat16* cur = (s & 1) ? abB : abA;
        __hip_bfloat16* nxt = (s & 1) ? abA : abB;
        const __hip_bfloat16* Wm = WmB + (size_t)layer * 2048 * 512;
        const __hip_bfloat16* Wz = Wrzn + (size_t)layer * 1536 * 1024;
        const __hip_bfloat16* Wn_h = Wnh + (size_t)layer * 512 * 512;
        const float* bm = bmsg + (size_t)layer * 2048;
        const float* bi = bih + (size_t)layer * 1536;
        const float* bh = bhh + (size_t)layer * 1536;

        // Msg = h @ Wm^T  (out 2048, K=512)
        gemm<0, 16><<<16 * 80, 256, 0, stream>>>(cur + 512, 1024, 512, Wm,
            nullptr, nullptr, nullptr, nullptr, Msg, 2048, nullptr);
        // inc = gather(Msg) + cnt*bm -> cur[0:512]
        gather_msum<<<NN / 4, 256, 0, stream>>>(bins, bcnt, bm, Msg, cur);
        // RZN = [sig r | sig z | i_n] = [inc|h] @ Wrzn^T + bi + bh(r,z)
        gemm<1, 12><<<12 * 80, 256, 0, stream>>>(cur, 1024, 1024, Wz,
            bi, bh, nullptr, nullptr, RZN, 1536, nullptr);
        // GRU combine fused into h @ Wnh^T epilogue -> h32, nxt h-slot
        gemm<2, 4><<<4 * 80, 256, 0, stream>>>(cur + 512, 1024, 512, Wn_h,
            bh + 1024, nullptr, RZN, h32, nxt + 512, 1024, nullptr);
    }
    // FC + column max (final h in abA h-slot after 4 steps)
    gemm<3, 4><<<4 * 80, 256, 0, stream>>>(abA + 512, 1024, 512, WfB,
        fcb, nullptr, nullptr, nullptr, nullptr, 0, om);
    writeout<<<1, 512, 0, stream>>>(om, out);
}

// Round 6
// 805.967 us; speedup vs baseline: 1.6662x; 1.0369x over previous
//
#include <hip/hip_runtime.h>
#include <hip/hip_bf16.h>

// GGNN encoder: N=10000, H=512, T=4, E=40000, L=2 x 2 timesteps.
// fp32 inputs, fp32 output, bf16 MFMA internally.
//
// Per step:
//   Msg  = h @ Wmsg_cat^T                (N x 2048, K=512)  [MODE 0, GX=16]
//   inc  = gather-sum(Msg) + cnt*b       (N x 512)          [gather_msum]
//   RZN  = [sig|sig|id]([inc|h] @ Wrzn^T + b) (N x 1536, K=1024) [MODE 1, GX=12]
//   h'   = GRU combine fused into h @ Wnh^T epilogue        [MODE 2, GX=4]
// Final: FC + column-max fused [MODE 3] -> writeout.
// GEMM K-loop is software-pipelined: double-buffered LDS, raw s_barrier +
// s_waitcnt vmcnt(4) so the k+1 global_load_lds prefetch stays in flight
// across the barrier (avoids the vmcnt(0) drain __syncthreads forces).

#define NN 10000
#define HD 512
#define NT 4
#define NE 40000
#define CAP 32
#define GYROWS 79          // ceil(10000/128)

typedef __bf16 bf16x8 __attribute__((ext_vector_type(8)));
typedef float f32x4 __attribute__((ext_vector_type(4)));
union V16 { int4 i; bf16x8 b; };

typedef __attribute__((address_space(1))) const unsigned int gu32;
typedef __attribute__((address_space(3))) unsigned int lu32;
__device__ __forceinline__ void gll16(const void* g, void* l) {
    __builtin_amdgcn_global_load_lds((gu32*)g, (lu32*)l, 16, 0, 0);
}

__device__ __forceinline__ float bf2f(__hip_bfloat16 v) { return __bfloat162float(v); }

__device__ __forceinline__ void f2b4(const float* __restrict__ s,
                                     __hip_bfloat16* __restrict__ d, int i) {
    float4 v = *(const float4*)(s + i);
    __hip_bfloat16 o[4] = {__float2bfloat16(v.x), __float2bfloat16(v.y),
                           __float2bfloat16(v.z), __float2bfloat16(v.w)};
    *(ulong1*)(d + i) = *(ulong1*)o;
}

// ---------------- fused prep: weights->bf16, Wrzn build, init, bins ---------
// SEG0 WmB 2048 blk | SEG1 Wrzn 3072 | SEG2 Wnh 512 | SEG3 WfB 256 |
// SEG4 init_h 5000 | SEG5 build_bins 625.  (1024 elems/blk for convs)
__global__ void prep_all(const float* __restrict__ Wmsg, const float* __restrict__ Wih,
                         const float* __restrict__ Whh, const float* __restrict__ fcW,
                         const float* __restrict__ x, const int* __restrict__ edges,
                         __hip_bfloat16* __restrict__ WmB, __hip_bfloat16* __restrict__ Wrzn,
                         __hip_bfloat16* __restrict__ WnhB, __hip_bfloat16* __restrict__ WfB,
                         float* __restrict__ h32, __hip_bfloat16* __restrict__ ab,
                         int* __restrict__ bcnt, int* __restrict__ bins) {
    int blk = blockIdx.x, tid = threadIdx.x;
    if (blk < 2048) { f2b4(Wmsg, WmB, blk * 1024 + tid * 4); return; }
    blk -= 2048;
    if (blk < 3072) {            // Wrzn: per layer 1536 rows x 1024 cols
        int i = blk * 1024 + tid * 4;
        int l = (i >= 1572864);
        int rem = i - l * 1572864;
        int r = rem >> 10, c = i & 1023;
        __hip_bfloat16 o[4];
        if (c < 512) {
            float4 v = *(const float4*)(Wih + (size_t)l * 786432 + (size_t)r * 512 + c);
            o[0] = __float2bfloat16(v.x); o[1] = __float2bfloat16(v.y);
            o[2] = __float2bfloat16(v.z); o[3] = __float2bfloat16(v.w);
        } else if (r < 1024) {
            float4 v = *(const float4*)(Whh + (size_t)l * 786432 + (size_t)r * 512 + (c - 512));
            o[0] = __float2bfloat16(v.x); o[1] = __float2bfloat16(v.y);
            o[2] = __float2bfloat16(v.z); o[3] = __float2bfloat16(v.w);
        } else {                 // n-gate rows, h-half: zero
            o[0] = o[1] = o[2] = o[3] = __float2bfloat16(0.f);
        }
        *(ulong1*)(Wrzn + i) = *(ulong1*)o;
        return;
    }
    blk -= 3072;
    if (blk < 512) {             // Wnh: rows 1024..1535 of each layer's Whh
        int i = blk * 1024 + tid * 4;
        int l = i >> 18, rem = i & 262143;
        float4 v = *(const float4*)(Whh + (size_t)l * 786432 + 524288 + rem);
        __hip_bfloat16 o[4] = {__float2bfloat16(v.x), __float2bfloat16(v.y),
                               __float2bfloat16(v.z), __float2bfloat16(v.w)};
        *(ulong1*)(WnhB + i) = *(ulong1*)o;
        return;
    }
    blk -= 512;
    if (blk < 256) { f2b4(fcW, WfB, blk * 1024 + tid * 4); return; }
    blk -= 256;
    if (blk < 5000) {            // init: h32 <- x, abA h-slot <- bf16(x)
        int i = blk * 1024 + tid * 4;
        float4 v = *(const float4*)(x + i);
        *(float4*)(h32 + i) = v;
        int m = i >> 9, c = i & 511;
        __hip_bfloat16 o[4] = {__float2bfloat16(v.x), __float2bfloat16(v.y),
                               __float2bfloat16(v.z), __float2bfloat16(v.w)};
        *(ulong1*)(ab + (size_t)m * 1024 + 512 + c) = *(ulong1*)o;
        return;
    }
    blk -= 5000;
    {                            // build_bins
        int i = blk * 256 + tid;
        if (i >= NT * NE) return;
        int src = edges[2 * i], tgt = edges[2 * i + 1];
        int t = i / NE;
        int b = tgt * NT + t;
        int pos = atomicAdd(&bcnt[b], 1);
        if (pos < CAP) bins[(size_t)b * CAP + pos] = src;
    }
}

// ---------------- gather: inc[n][c] = sum_t sum_src Msg[src][t*512+c] + cnt*bm
__global__ __launch_bounds__(256) void gather_msum(
    const int* __restrict__ bins, const int* __restrict__ bcnt,
    const float* __restrict__ bm, const __hip_bfloat16* __restrict__ Msg,
    __hip_bfloat16* __restrict__ inc) {
    int wave = threadIdx.x >> 6, lane = threadIdx.x & 63;
    int n = blockIdx.x * 4 + wave;
    int co = lane * 8;
    float acc[8] = {0, 0, 0, 0, 0, 0, 0, 0};
#pragma unroll
    for (int t = 0; t < NT; ++t) {
        int bi = n * NT + t;
        int cnt = bcnt[bi]; if (cnt > CAP) cnt = CAP;
        const int* bl = bins + (size_t)bi * CAP;
        for (int e = 0; e < cnt; ++e) {
            int src = bl[e];
            V16 v; v.i = *(const int4*)(Msg + (size_t)src * 2048 + t * 512 + co);
#pragma unroll
            for (int k = 0; k < 8; ++k) acc[k] += (float)v.b[k];
        }
        float4 b0 = *(const float4*)(bm + t * 512 + co);
        float4 b1 = *(const float4*)(bm + t * 512 + co + 4);
        float fc = (float)cnt;
        acc[0] += fc * b0.x; acc[1] += fc * b0.y; acc[2] += fc * b0.z; acc[3] += fc * b0.w;
        acc[4] += fc * b1.x; acc[5] += fc * b1.y; acc[6] += fc * b1.z; acc[7] += fc * b1.w;
    }
    V16 o;
#pragma unroll
    for (int k = 0; k < 8; ++k) o.b[k] = (__bf16)acc[k];
    *(int4*)(inc + (size_t)n * 1024 + co) = o.i;
}

// ---------------- monotone-uint float max encoding ----------------
__device__ __forceinline__ unsigned fenc(float f) {
    unsigned b = __float_as_uint(f);
    return b ^ (((int)b >> 31) | 0x80000000u);
}
__device__ __forceinline__ float fdec(unsigned u) {
    unsigned b = (u & 0x80000000u) ? (u ^ 0x80000000u) : ~u;
    return __uint_as_float(b);
}

// ---------------- GEMM: out = A(NNxK,lda) @ W^T, 128x128 tile, XCD swizzle ---
// Software-pipelined K-loop (2-buffer LDS, fine vmcnt, raw barriers).
// MODE 0: obf[m*2048+col] = bf16(acc)                              (Msg)
// MODE 1: v=acc+b0+b1(col<1024); obf = bf16(col<1024?sigmoid(v):v) (RZN)
// MODE 2: v=acc+b0; GRU combine with RZN -> h32, obf (next h-slot)
// MODE 3: v=acc+b0; column max -> om                               (FC)
template<int MODE, int GX>
__global__ __launch_bounds__(256) void gemm(
    const __hip_bfloat16* __restrict__ A, int lda, int K,
    const __hip_bfloat16* __restrict__ W,
    const float* __restrict__ b0, const float* __restrict__ b1,
    const __hip_bfloat16* __restrict__ RZN,
    float* __restrict__ h32, __hip_bfloat16* __restrict__ obf, int ldo,
    unsigned* __restrict__ om) {
    __shared__ int4 sA4[2][512];
    __shared__ int4 sB4[2][512];
    __shared__ unsigned sm[128];
    int bid = blockIdx.x;
    int xcd = bid & 7, slot = bid >> 3;
    int brow = (slot / GX) * 8 + xcd;
    if (brow >= GYROWS) return;
    int bcol = slot % GX;
    int m0 = brow * 128, n0 = bcol * 128;

    int tid = threadIdx.x;
    int lane = tid & 63, wave = tid >> 6;
    int wr = wave >> 1, wc = wave & 1;
    int lm = lane & 15, quad = lane >> 4;

    const int KT = K >> 5;
    auto issue = [&](int kt, int p) {
        int k0 = kt << 5;
#pragma unroll
        for (int it = 0; it < 2; ++it) {
            int idx = it * 256 + tid;
            int row = idx >> 2, kc = idx & 3;
            int gm = m0 + row; gm = gm < NN ? gm : NN - 1;
            gll16(A + (size_t)gm * lda + k0 + kc * 8, (__hip_bfloat16*)(sA4[p]) + idx * 8);
            gll16(W + (size_t)(n0 + row) * K + k0 + kc * 8, (__hip_bfloat16*)(sB4[p]) + idx * 8);
        }
    };

    f32x4 acc[4][4] = {};
    issue(0, 0);                     // 4 loads/thread in flight
    for (int kt = 0; kt < KT; ++kt) {
        int p = kt & 1;
        if (kt + 1 < KT) {
            issue(kt + 1, 1 - p);                  // 4 more; 8 outstanding
            __builtin_amdgcn_s_waitcnt(0xF74);     // vmcnt(4): tile-k loads done
        } else {
            __builtin_amdgcn_s_waitcnt(0xF70);     // vmcnt(0)
        }
        __builtin_amdgcn_s_barrier();              // all waves' tile-k in LDS
        __builtin_amdgcn_sched_barrier(0);
        V16 a[4], b[4];
#pragma unroll
        for (int i = 0; i < 4; ++i) {
            a[i].i = sA4[p][(wr * 64 + i * 16 + lm) * 4 + quad];
            b[i].i = sB4[p][(wc * 64 + i * 16 + lm) * 4 + quad];
        }
#pragma unroll
        for (int i = 0; i < 4; ++i)
#pragma unroll
            for (int j = 0; j < 4; ++j)
                acc[i][j] = __builtin_amdgcn_mfma_f32_16x16x32_bf16(a[i].b, b[j].b, acc[i][j], 0, 0, 0);
        __builtin_amdgcn_sched_barrier(0);
        __builtin_amdgcn_s_barrier();              // done reading buf p (iter k+2 rewrites it)
    }
    if (MODE == 3) {
        if (tid < 128) sm[tid] = 0;
        __syncthreads();
    }
#pragma unroll
    for (int j = 0; j < 4; ++j) {
        int c = wc * 64 + j * 16 + lm;
        int col = n0 + c;
        float bias = 0.f;
        if (MODE == 1) bias = b0[col] + (col < 1024 ? b1[col] : 0.f);
        if (MODE == 2 || MODE == 3) bias = b0[col];
        float mx = -INFINITY;
#pragma unroll
        for (int i = 0; i < 4; ++i) {
            int r0 = m0 + wr * 64 + i * 16 + quad * 4;
#pragma unroll
            for (int r = 0; r < 4; ++r) {
                int m = r0 + r;
                if (m >= NN) continue;
                float v = acc[i][j][r] + bias;
                if (MODE == 0) {
                    obf[(size_t)m * 2048 + col] = __float2bfloat16(v);
                } else if (MODE == 1) {
                    float o = (col < 1024) ? 1.f / (1.f + __expf(-v)) : v;
                    obf[(size_t)m * 1536 + col] = __float2bfloat16(o);
                } else if (MODE == 2) {
                    size_t rz = (size_t)m * 1536;
                    float rg = bf2f(RZN[rz + col]);
                    float zg = bf2f(RZN[rz + 512 + col]);
                    float inn = bf2f(RZN[rz + 1024 + col]);
                    float nx = inn + rg * v;
                    float n = 1.f - 2.f / (__expf(2.f * nx) + 1.f);
                    size_t o = (size_t)m * 512 + col;
                    float hnew = (1.f - zg) * n + zg * h32[o];
                    h32[o] = hnew;
                    obf[(size_t)m * ldo + col] = __float2bfloat16(hnew);
                } else {
                    mx = fmaxf(mx, v);
                }
            }
        }
        if (MODE == 3) atomicMax(&sm[c], fenc(mx));
    }
    if (MODE == 3) {
        __syncthreads();
        if (tid < 128) atomicMax(&om[n0 + tid], sm[tid]);
    }
}

__global__ void writeout(const unsigned* __restrict__ om, float* __restrict__ o) {
    int c = threadIdx.x;
    o[c] = fdec(om[c]);
}

// ---------------- launch ----------------
extern "C" void kernel_launch(void* const* d_in, const int* in_sizes, int n_in,
                              void* d_out, int out_size, void* d_ws, size_t ws_size,
                              hipStream_t stream) {
    (void)in_sizes; (void)n_in; (void)out_size; (void)ws_size;
    const float* x    = (const float*)d_in[0];
    const int*   edges= (const int*)d_in[1];
    const float* Wmsg = (const float*)d_in[2];
    const float* bmsg = (const float*)d_in[3];
    const float* Wih  = (const float*)d_in[4];
    const float* Whh  = (const float*)d_in[5];
    const float* bih  = (const float*)d_in[6];
    const float* bhh  = (const float*)d_in[7];
    const float* fcW  = (const float*)d_in[8];
    const float* fcb  = (const float*)d_in[9];
    float* out = (float*)d_out;

    char* ws = (char*)d_ws;
    size_t off = 0;
    auto alloc = [&](size_t bytes) -> void* {
        void* p = ws + off; off += (bytes + 255) & ~(size_t)255; return p;
    };
    float*          h32  = (float*)alloc((size_t)NN * HD * 4);              // 20.5 MB
    __hip_bfloat16* abA  = (__hip_bfloat16*)alloc((size_t)NN * 1024 * 2);   // 20.5 MB
    __hip_bfloat16* abB  = (__hip_bfloat16*)alloc((size_t)NN * 1024 * 2);   // 20.5 MB
    int*            bcnt = (int*)alloc((size_t)NN * NT * 4);                // 160 KB
    int*            bins = (int*)alloc((size_t)NN * NT * CAP * 4);          // 5.1 MB
    unsigned*       om   = (unsigned*)alloc(HD * 4);
    __hip_bfloat16* WmB  = (__hip_bfloat16*)alloc((size_t)2 * 2048 * 512 * 2);  // 4.2 MB
    __hip_bfloat16* Wrzn = (__hip_bfloat16*)alloc((size_t)2 * 1536 * 1024 * 2); // 6.3 MB
    __hip_bfloat16* Wnh  = (__hip_bfloat16*)alloc((size_t)2 * 512 * 512 * 2);   // 1.05 MB
    __hip_bfloat16* WfB  = (__hip_bfloat16*)alloc((size_t)512 * 512 * 2);       // 0.5 MB
    // union: Msg (41 MB) xor RZN (30.7 MB)
    char* uni = (char*)alloc((size_t)NN * 2048 * 2);                        // 41 MB
    __hip_bfloat16* Msg = (__hip_bfloat16*)uni;
    __hip_bfloat16* RZN = (__hip_bfloat16*)uni;
    // total ~120 MB

    hipMemsetAsync(bcnt, 0, (size_t)NN * NT * 4, stream);
    hipMemsetAsync(om, 0, HD * 4, stream);
    prep_all<<<2048 + 3072 + 512 + 256 + 5000 + 625, 256, 0, stream>>>(
        Wmsg, Wih, Whh, fcW, x, edges, WmB, Wrzn, Wnh, WfB, h32, abA, bcnt, bins);

    for (int s = 0; s < 4; ++s) {
        int layer = s >> 1;
        __hip_bfloat16* cur = (s & 1) ? abB : abA;
        __hip_bfloat16* nxt = (s & 1) ? abA : abB;
        const __hip_bfloat16* Wm = WmB + (size_t)layer * 2048 * 512;
        const __hip_bfloat16* Wz = Wrzn + (size_t)layer * 1536 * 1024;
        const __hip_bfloat16* Wn_h = Wnh + (size_t)layer * 512 * 512;
        const float* bm = bmsg + (size_t)layer * 2048;
        const float* bi = bih + (size_t)layer * 1536;
        const float* bh = bhh + (size_t)layer * 1536;

        // Msg = h @ Wm^T  (out 2048, K=512)
        gemm<0, 16><<<16 * 80, 256, 0, stream>>>(cur + 512, 1024, 512, Wm,
            nullptr, nullptr, nullptr, nullptr, Msg, 2048, nullptr);
        // inc = gather(Msg) + cnt*bm -> cur[0:512]
        gather_msum<<<NN / 4, 256, 0, stream>>>(bins, bcnt, bm, Msg, cur);
        // RZN = [sig r | sig z | i_n] = [inc|h] @ Wrzn^T + bi + bh(r,z)
        gemm<1, 12><<<12 * 80, 256, 0, stream>>>(cur, 1024, 1024, Wz,
            bi, bh, nullptr, nullptr, RZN, 1536, nullptr);
        // GRU combine fused into h @ Wnh^T epilogue -> h32, nxt h-slot
        gemm<2, 4><<<4 * 80, 256, 0, stream>>>(cur + 512, 1024, 512, Wn_h,
            bh + 1024, nullptr, RZN, h32, nxt + 512, 1024, nullptr);
    }
    // FC + column max (final h in abA h-slot after 4 steps)
    gemm<3, 4><<<4 * 80, 256, 0, stream>>>(abA + 512, 1024, 512, WfB,
        fcb, nullptr, nullptr, nullptr, nullptr, 0, om);
    writeout<<<1, 512, 0, stream>>>(om, out);
}